// Round 1
// baseline (1257.719 us; speedup 1.0000x reference)
//
#include <hip/hip_runtime.h>
#include <hip/hip_bf16.h>

// Problem: BS=8, NF=64, N=2048, J=3, NOUT=64, C=2*NOUT=128
// out = [zbn (8*128*2048 fp32), W (8*2048*2048*3 fp32 pass-through)]
// ws layout: [0, 2MB): X as bf16 (1M elems); [2MB, +1KB): stats S1[128],S2[128],scale[128],shift[128]

#define EPSV 1e-5f
#define ZBN_ELEMS (8*128*2048)

typedef __bf16 bf16x8 __attribute__((ext_vector_type(8)));
typedef float  f32x4  __attribute__((ext_vector_type(4)));
typedef float  f4v    __attribute__((ext_vector_type(4)));

union BF8 { unsigned short u[8]; bf16x8 v; };

__device__ __forceinline__ unsigned short f2bf(float f) {
    unsigned u = __float_as_uint(f);
    u += 0x7fffu + ((u >> 16) & 1u);   // round-to-nearest-even (inputs are finite)
    return (unsigned short)(u >> 16);
}

// ---------------- kernel 1: X fp32 -> bf16, zero stats ----------------
__global__ void prep_kernel(const float* __restrict__ X,
                            unsigned short* __restrict__ Xbf,
                            float* __restrict__ stats) {
    int t = blockIdx.x * 256 + threadIdx.x;      // grid sized exactly to 1048576
    Xbf[t] = f2bf(X[t]);
    if (blockIdx.x == 0 && threadIdx.x < 256) stats[threadIdx.x] = 0.0f;
}

// ---------------- kernel 2: GEMM (W*X^T) + W write-through + conv + stats ----------------
// grid = 256 blocks (8 b * 32 mtiles), 256 threads (4 waves).
// wave w handles m in [mt*64 + w*16, +16), all 64 f, all 3 j.
// MFMA 16x16x32 bf16 layouts (HW-verified per guide):
//   A[m=lane&15][k=(lane>>4)*8+e], B[k=(lane>>4)*8+e][n=lane&15], D: col=lane&15, row=(lane>>4)*4+reg
__global__ __launch_bounds__(256, 1) void gemm_conv_kernel(
    const float* __restrict__ W,
    const unsigned short* __restrict__ Xbf,
    const float* __restrict__ cv1_w, const float* __restrict__ cv1_b,
    const float* __restrict__ cv2_w, const float* __restrict__ cv2_b,
    float* __restrict__ out, float* __restrict__ stats)
{
    __shared__ unsigned short x1s[64][200];   // [m_local][i=j*64+f] bf16, pad 192->200 (400B rows, 16B-aligned)

    const int tid  = threadIdx.x;
    const int w    = tid >> 6;
    const int lane = tid & 63;
    const int q    = lane >> 4;
    const int l15  = lane & 15;
    const int bx   = blockIdx.x;
    const int b    = bx >> 5;
    const int mt   = bx & 31;

    const int m_global = mt * 64 + w * 16 + l15;     // A-operand row for this lane
    const float* Wrow = W   + (size_t)(b * 2048 + m_global) * 6144;          // 2048*3 floats per m-row
    float*       Wout = out + (size_t)ZBN_ELEMS + (size_t)(b * 2048 + m_global) * 6144;
    const unsigned short* Xb = Xbf + b * (64 * 2048);

    f32x4 acc[4][3];
    #pragma unroll
    for (int ft = 0; ft < 4; ++ft)
        #pragma unroll
        for (int j = 0; j < 3; ++j)
            acc[ft][j] = (f32x4)0.0f;

    // ---- K loop: 2048 / 32 = 64 steps ----
    #pragma unroll 2
    for (int kt = 0; kt < 64; ++kt) {
        const int n0 = kt * 32 + q * 8;              // this lane's 8 n-values (k = q*8+e)
        // W: 24 contiguous floats = W[b][m][n0..n0+7][j=0..2]
        const f4v* wp = (const f4v*)(Wrow + n0 * 3);
        f4v wv[6];
        #pragma unroll
        for (int i = 0; i < 6; ++i) wv[i] = __builtin_nontemporal_load(wp + i);
        // write-through W to output (exact fp32 copy, saves a 402MB re-read)
        f4v* wo = (f4v*)(Wout + n0 * 3);
        #pragma unroll
        for (int i = 0; i < 6; ++i) __builtin_nontemporal_store(wv[i], wo + i);

        const float* wf = (const float*)wv;
        BF8 a[3];
        #pragma unroll
        for (int j = 0; j < 3; ++j)
            #pragma unroll
            for (int e = 0; e < 8; ++e)
                a[j].u[e] = f2bf(wf[e * 3 + j]);

        BF8 bfr[4];
        #pragma unroll
        for (int ft = 0; ft < 4; ++ft)
            bfr[ft].v = *(const bf16x8*)(Xb + (ft * 16 + l15) * 2048 + n0);  // 16B aligned

        #pragma unroll
        for (int ft = 0; ft < 4; ++ft)
            #pragma unroll
            for (int j = 0; j < 3; ++j)
                acc[ft][j] = __builtin_amdgcn_mfma_f32_16x16x32_bf16(a[j].v, bfr[ft].v, acc[ft][j], 0, 0, 0);
    }

    // ---- spill x1 tile to LDS as bf16: x1s[m_local][i] ----
    #pragma unroll
    for (int ft = 0; ft < 4; ++ft)
        #pragma unroll
        for (int j = 0; j < 3; ++j)
            #pragma unroll
            for (int r = 0; r < 4; ++r)
                x1s[w * 16 + q * 4 + r][j * 64 + ft * 16 + l15] = f2bf(acc[ft][j][r]);
    __syncthreads();

    // ---- conv as second MFMA: zb[c][m] = relu(cvw[c][:] . x1[:][m] + bias) ----
    // wave w handles c in [w*32, w*32+32) (2 c-tiles), all 64 m (4 n-tiles), K=192 (6 k-tiles)
    f32x4 acc2[2][4];
    #pragma unroll
    for (int ctl = 0; ctl < 2; ++ctl)
        #pragma unroll
        for (int nt = 0; nt < 4; ++nt)
            acc2[ctl][nt] = (f32x4)0.0f;

    #pragma unroll
    for (int kt = 0; kt < 6; ++kt) {
        const int i0 = kt * 32 + q * 8;
        BF8 afr[2];
        #pragma unroll
        for (int ctl = 0; ctl < 2; ++ctl) {
            const int c = (2 * w + ctl) * 16 + l15;
            // channels 0..63 = cv2 (yl1), 64..127 = cv1 (z1)  [concat order in reference]
            const float* wr = (c < 64) ? (cv2_w + c * 192) : (cv1_w + (c - 64) * 192);
            #pragma unroll
            for (int e = 0; e < 8; ++e) afr[ctl].u[e] = f2bf(wr[i0 + e]);
        }
        BF8 bfr2[4];
        #pragma unroll
        for (int nt = 0; nt < 4; ++nt)
            bfr2[nt].v = *(const bf16x8*)(&x1s[nt * 16 + l15][i0]);
        #pragma unroll
        for (int ctl = 0; ctl < 2; ++ctl)
            #pragma unroll
            for (int nt = 0; nt < 4; ++nt)
                acc2[ctl][nt] = __builtin_amdgcn_mfma_f32_16x16x32_bf16(afr[ctl].v, bfr2[nt].v, acc2[ctl][nt], 0, 0, 0);
    }

    // ---- bias + relu + store zb + per-channel stats ----
    #pragma unroll
    for (int ctl = 0; ctl < 2; ++ctl) {
        #pragma unroll
        for (int r = 0; r < 4; ++r) {
            const int c = (2 * w + ctl) * 16 + q * 4 + r;
            const float bias = (c < 64) ? cv2_b[c] : cv1_b[c - 64];
            float s1 = 0.0f, s2 = 0.0f;
            #pragma unroll
            for (int nt = 0; nt < 4; ++nt) {
                float zv = acc2[ctl][nt][r] + bias;
                zv = fmaxf(zv, 0.0f);
                out[((size_t)(b * 128 + c) << 11) + mt * 64 + nt * 16 + l15] = zv;
                s1 += zv;
                s2 += zv * zv;
            }
            // butterfly over the 16 lanes holding different m (stays within quad group)
            #pragma unroll
            for (int msk = 1; msk < 16; msk <<= 1) {
                s1 += __shfl_xor(s1, msk);
                s2 += __shfl_xor(s2, msk);
            }
            if (l15 == 0) {
                atomicAdd(&stats[c], s1);
                atomicAdd(&stats[128 + c], s2);
            }
        }
    }
}

// ---------------- kernel 3: finalize BN scale/shift ----------------
__global__ void finalize_kernel(const float* __restrict__ stats,
                                const float* __restrict__ Nb,
                                const float* __restrict__ gamma,
                                const float* __restrict__ beta,
                                float* __restrict__ ss) {
    int c = threadIdx.x;   // 128 threads
    float total = 0.0f;
    #pragma unroll
    for (int i = 0; i < 8; ++i) total += Nb[i];
    float mean = stats[c] / total;
    float var  = stats[128 + c] / total - mean * mean;
    float inv  = rsqrtf(var + EPSV);
    float sc   = gamma[c] * inv;
    ss[c]       = sc;
    ss[128 + c] = beta[c] - mean * sc;
}

// ---------------- kernel 4: in-place normalize zbn = (zb*sc+sh)*mask ----------------
__global__ void norm_kernel(float* __restrict__ out,
                            const float* __restrict__ ss,
                            const float* __restrict__ mask) {
    int t = blockIdx.x * 256 + threadIdx.x;      // over float4, 524288 total (exact)
    float4 v = ((const float4*)out)[t];
    int row = t >> 9;                            // 512 float4 per (b,c) row
    int c = row & 127;
    int b = row >> 7;
    float sc = ss[c], sh = ss[128 + c];
    float4 mk = ((const float4*)mask)[(b << 9) + (t & 511)];
    float4 r;
    r.x = (v.x * sc + sh) * mk.x;
    r.y = (v.y * sc + sh) * mk.y;
    r.z = (v.z * sc + sh) * mk.z;
    r.w = (v.w * sc + sh) * mk.w;
    ((float4*)out)[t] = r;
}

extern "C" void kernel_launch(void* const* d_in, const int* in_sizes, int n_in,
                              void* d_out, int out_size, void* d_ws, size_t ws_size,
                              hipStream_t stream) {
    const float* X     = (const float*)d_in[0];
    const float* W     = (const float*)d_in[1];
    const float* Nb    = (const float*)d_in[2];
    const float* mask  = (const float*)d_in[3];
    const float* cv1_w = (const float*)d_in[4];
    const float* cv1_b = (const float*)d_in[5];
    const float* cv2_w = (const float*)d_in[6];
    const float* cv2_b = (const float*)d_in[7];
    const float* gamma = (const float*)d_in[8];
    const float* beta  = (const float*)d_in[9];
    float* out = (float*)d_out;

    unsigned short* Xbf = (unsigned short*)d_ws;
    float* stats = (float*)((char*)d_ws + (size_t)2 * 1024 * 1024);  // needs ws >= 2MB+1KB
    float* ss    = stats + 256;

    hipLaunchKernelGGL(prep_kernel,      dim3(4096), dim3(256), 0, stream, X, Xbf, stats);
    hipLaunchKernelGGL(gemm_conv_kernel, dim3(256),  dim3(256), 0, stream,
                       W, Xbf, cv1_w, cv1_b, cv2_w, cv2_b, out, stats);
    hipLaunchKernelGGL(finalize_kernel,  dim3(1),    dim3(128), 0, stream, stats, Nb, gamma, beta, ss);
    hipLaunchKernelGGL(norm_kernel,      dim3(2048), dim3(256), 0, stream, out, ss, mask);
}